// Round 7
// baseline (22.472 us; speedup 1.0000x reference)
//
#include <hip/hip_runtime.h>
#include <math.h>

#define Bn 16
#define Cn 10
#define Hn 400
#define Wn 352
#define Nn 50
#define PLANE (Hn * Wn)             // 140800 floats = 35200 float4
#define NCHUNK 32
#define VPER (PLANE / 4 / NCHUNK)   // 1100 float4 per chunk
#define BKG_THRESH 0.025f
#define LOG_CLAMP -100.0f

// ws layout (floats), SoA for coalesced reads in kernel B:
//   [0    ..  512)  sig partials   (Bn*NCHUNK)
//   [512  .. 1024)  log partials
//   [1024 .. 1536)  cnt partials
//   [2048 .. 2208)  pointvals (Bn*10)
#define WS_SIG 0
#define WS_LOG 512
#define WS_CNT 1024
#define WS_PV  2048

__device__ __forceinline__ float softplusf(float x) {   // stable log(1+exp(x))
    return fmaxf(x, 0.0f) + log1pf(expf(-fabsf(x)));
}
__device__ __forceinline__ float sigmoidf(float x) {
    return 1.0f / (1.0f + expf(-x));
}
__device__ __forceinline__ float wave_sum(float v) {
    for (int off = 32; off > 0; off >>= 1) v += __shfl_down(v, off);
    return __shfl(v, 0);
}

// ---------------- kernel A: point work (16 blocks) + plane chunks (512) -----
__global__ __launch_bounds__(256) void partial_kernel(const float* __restrict__ out,
                                                      const float* __restrict__ tgt,
                                                      float* __restrict__ ws) {
    const int tid = threadIdx.x;

    if (blockIdx.x < Bn) {
        // ======== point work: one wave per sample, dispatched FIRST ========
        if (tid >= 64) return;
        const int b    = blockIdx.x;
        const int lane = tid;

        const float* t = tgt + (size_t)b * Nn * 7;
        const bool active = lane < Nn;
        float tx = 0.0f, ty = 0.0f, t2 = 0.0f, t3 = 1.0f, t4 = 1.0f, t5 = 1.0f, ang = 0.0f;
        int key = -1;
        if (active) {
            tx = t[lane * 7 + 0] * 2.0f;
            ty = t[lane * 7 + 1] * 2.0f;
            t2 = t[lane * 7 + 2];
            t3 = t[lane * 7 + 3];
            t4 = t[lane * 7 + 4];
            t5 = t[lane * 7 + 5];
            ang = t[lane * 7 + 6];
            int dx = (int)floorf(tx);
            int dy = (int)floorf(ty);
            key = dx * Wn + dy;
        }

        // gather the 10 channels at the point (issue ASAP, one latency round)
        const float* base = out + (size_t)b * Cn * PLANE;
        float g[10];
        #pragma unroll
        for (int c = 0; c < 10; ++c) g[c] = active ? base[(size_t)c * PLANE + key] : 0.0f;

        // first-occurrence dedupe via shuffles (mask semantics: unique cells)
        bool isfirst = active;
        #pragma unroll 1
        for (int m = 0; m < Nn; ++m) {
            int km = __shfl(key, m);
            if (active && m < lane && km == key) isfirst = false;
        }

        // corrections for masked (unique) points
        float c_sig = 0.0f, c_log = 0.0f, c_cnt = 0.0f, c_n = 0.0f;
        if (isfirst) {
            float p = sigmoidf(g[0]);
            c_sig = p;
            c_n = 1.0f;
            if (p > BKG_THRESH) {
                c_cnt = 1.0f;
                c_log = fmaxf(-softplusf(g[0]), LOG_CLAMP);
            }
        }

        // per-point losses (ALL 50 points, duplicates included)
        float v_obj = 0.0f, v_xyz = 0.0f, v_hwl = 0.0f, v_acl = 0.0f, v_asin = 0.0f;
        if (active) {
            v_obj = -fmaxf(-softplusf(-g[0]), LOG_CLAMP);

            float fx = tx - floorf(tx);
            float fy = ty - floorf(ty);
            float tz = t2 * 0.25f;                 // / ZSIZE (=4.0)
            float e0 = sigmoidf(g[1]) - fx;
            float e1 = sigmoidf(g[2]) - fy;
            float e2 = sigmoidf(g[3]) - tz;
            v_xyz = e0 * e0 + e1 * e1 + e2 * e2;

            float h0 = g[4] - logf(t3 / 1.52f);
            float h1 = g[5] - logf(t4 / 1.63f);
            float h2 = g[6] - logf(t5 / 3.88f);
            v_hwl = h0 * h0 + h1 * h1 + h2 * h2;

            float m = fmaxf(g[7], g[8]);
            float lse = m + logf(expf(g[7] - m) + expf(g[8] - m));
            float gsel = (ang >= 0.0f) ? g[8] : g[7];
            v_acl = lse - gsel;

            float d = sinf(g[9]) - sinf(sinf(ang));
            float ad = fabsf(d);
            v_asin = (ad < 1.0f) ? 0.5f * d * d : ad - 0.5f;
        }
        v_obj  = wave_sum(v_obj);
        v_xyz  = wave_sum(v_xyz);
        v_hwl  = wave_sum(v_hwl);
        v_acl  = wave_sum(v_acl);
        v_asin = wave_sum(v_asin);
        c_sig  = wave_sum(c_sig);
        c_log  = wave_sum(c_log);
        c_cnt  = wave_sum(c_cnt);
        c_n    = wave_sum(c_n);

        if (lane == 0) {
            float* pv = ws + WS_PV + (size_t)b * 10;
            pv[0] = v_obj;  pv[1] = v_xyz; pv[2] = v_hwl; pv[3] = v_acl; pv[4] = v_asin;
            pv[5] = c_sig;  pv[6] = c_log; pv[7] = c_cnt; pv[8] = c_n;
        }
        return;
    }

    // ======== plane chunk reduce over channel-0 plane ========
    const int idx = blockIdx.x - Bn;
    const int b  = idx >> 5;
    const int ch = idx & 31;
    const float4* plane = (const float4*)(out + (size_t)b * Cn * PLANE);
    const int i0 = ch * VPER + tid;

    // issue ALL loads (4 + conditional tail) before any processing: one
    // HBM latency round instead of two for the tail waves.
    float4 v0 = plane[i0];
    float4 v1 = plane[i0 + 256];
    float4 v2 = plane[i0 + 512];
    float4 v3 = plane[i0 + 768];
    const bool has_tail = tid < VPER - 1024;   // 76 tail threads
    float4 v4 = make_float4(0.0f, 0.0f, 0.0f, 0.0f);
    if (has_tail) v4 = plane[i0 + 1024];

    float s_sig = 0.0f, s_log = 0.0f, s_cnt = 0.0f;
    float xs[20];
    xs[0]=v0.x;  xs[1]=v0.y;  xs[2]=v0.z;  xs[3]=v0.w;
    xs[4]=v1.x;  xs[5]=v1.y;  xs[6]=v1.z;  xs[7]=v1.w;
    xs[8]=v2.x;  xs[9]=v2.y;  xs[10]=v2.z; xs[11]=v2.w;
    xs[12]=v3.x; xs[13]=v3.y; xs[14]=v3.z; xs[15]=v3.w;
    xs[16]=v4.x; xs[17]=v4.y; xs[18]=v4.z; xs[19]=v4.w;
    const int nel = has_tail ? 20 : 16;
    #pragma unroll
    for (int k = 0; k < 20; ++k) {
        if (k >= nel) break;
        float x = xs[k];
        // shared transcendental: e = exp(-|x|); sigmoid & softplus from it
        float e   = expf(-fabsf(x));
        float inv = 1.0f / (1.0f + e);
        float p   = (x >= 0.0f) ? inv : e * inv;
        float sp  = fmaxf(x, 0.0f) + log1pf(e);   // softplus(x)
        s_sig += p;
        bool sel = p > BKG_THRESH;
        s_cnt += sel ? 1.0f : 0.0f;
        s_log += sel ? fmaxf(-sp, LOG_CLAMP) : 0.0f;
    }

    s_sig = wave_sum(s_sig);
    s_log = wave_sum(s_log);
    s_cnt = wave_sum(s_cnt);

    __shared__ float sh[4][3];
    const int wv = tid >> 6, lane6 = tid & 63;
    if (lane6 == 0) { sh[wv][0] = s_sig; sh[wv][1] = s_log; sh[wv][2] = s_cnt; }
    __syncthreads();
    if (tid == 0) {
        const int slot = b * NCHUNK + ch;
        ws[WS_SIG + slot] = sh[0][0] + sh[1][0] + sh[2][0] + sh[3][0];
        ws[WS_LOG + slot] = sh[0][1] + sh[1][1] + sh[2][1] + sh[3][1];
        ws[WS_CNT + slot] = sh[0][2] + sh[1][2] + sh[2][2] + sh[3][2];
    }
}

// ---------------- kernel B: combine + finalize (1 block, 4 waves) ----------
__global__ __launch_bounds__(256) void finalize_kernel(const float* __restrict__ ws,
                                                       float* __restrict__ out7) {
    const int w    = threadIdx.x >> 6;   // wave: samples 4w..4w+3
    const int lane = threadIdx.x & 63;

    __shared__ float sh_terms[Bn][6];

    #pragma unroll
    for (int s = 0; s < 4; ++s) {
        const int b = (w << 2) + s;

        // issue pv loads early so they overlap the partial reduction
        float pvl = (lane < 9) ? ws[WS_PV + (size_t)b * 10 + lane] : 0.0f;

        float a0 = 0.0f, a1 = 0.0f, a2 = 0.0f;
        if (lane < NCHUNK) {
            const int slot = b * NCHUNK + lane;
            a0 = ws[WS_SIG + slot];
            a1 = ws[WS_LOG + slot];
            a2 = ws[WS_CNT + slot];
        }
        a0 = wave_sum(a0);   // s_sig
        a1 = wave_sum(a1);   // s_log
        a2 = wave_sum(a2);   // s_cnt

        float v_obj  = __shfl(pvl, 0);
        float v_xyz  = __shfl(pvl, 1);
        float v_hwl  = __shfl(pvl, 2);
        float v_acl  = __shfl(pvl, 3);
        float v_asin = __shfl(pvl, 4);
        float c_sig  = __shfl(pvl, 5);
        float c_log  = __shfl(pvl, 6);
        float c_cnt  = __shfl(pvl, 7);
        float c_n    = __shfl(pvl, 8);

        if (lane == 0) {
            float nbkg    = (float)PLANE - c_n;
            float sig_bkg = a0 - c_sig;
            float clsscale = expf(-3.0f * sig_bkg / nbkg) * 2.5f;

            float cntv = a2 - c_cnt;
            float slog = a1 - c_log;
            float bkg_l = (cntv > 0.0f) ? (-slog / fmaxf(cntv, 1.0f)) : 0.0f;

            const float invN  = 1.0f / (float)Nn;
            const float invN3 = 1.0f / (float)(Nn * 3);

            sh_terms[b][0] = bkg_l;
            sh_terms[b][1] = v_obj * invN * clsscale;
            sh_terms[b][2] = v_xyz * invN3;
            sh_terms[b][3] = v_hwl * invN3 * 0.5f;
            sh_terms[b][4] = v_acl * invN * 0.5f;
            sh_terms[b][5] = v_asin * invN * 0.5f;
        }
    }
    __syncthreads();

    if (threadIdx.x == 0) {
        float s[6] = {0, 0, 0, 0, 0, 0};
        for (int bb = 0; bb < Bn; ++bb)
            for (int j = 0; j < 6; ++j)
                s[j] += sh_terms[bb][j];
        float tot = 0.0f;
        for (int j = 0; j < 6; ++j) tot += s[j];
        out7[0] = tot;
        for (int j = 0; j < 6; ++j) out7[1 + j] = s[j];
    }
}

extern "C" void kernel_launch(void* const* d_in, const int* in_sizes, int n_in,
                              void* d_out, int out_size, void* d_ws, size_t ws_size,
                              hipStream_t stream) {
    const float* out = (const float*)d_in[0];   // (B, C, H, W) f32
    const float* tgt = (const float*)d_in[1];   // (B, N, 7)   f32
    float* o  = (float*)d_out;                  // 7 floats
    float* ws = (float*)d_ws;

    partial_kernel<<<Bn * NCHUNK + Bn, 256, 0, stream>>>(out, tgt, ws);
    finalize_kernel<<<1, 256, 0, stream>>>(ws, o);
}

// Round 8
// 19.536 us; speedup vs baseline: 1.1503x; 1.1503x over previous
//
#include <hip/hip_runtime.h>
#include <math.h>

#define Bn 16
#define Cn 10
#define Hn 400
#define Wn 352
#define Nn 50
#define PLANE (Hn * Wn)             // 140800 floats = 35200 float4
#define NCHUNK 32
#define VPER (PLANE / 4 / NCHUNK)   // 1100 float4 per chunk
#define BKG_THRESH 0.025f
#define LOG_CLAMP -100.0f

// ws layout (floats), SoA for coalesced reads in kernel B:
//   [0    ..  512)  sig partials   (Bn*NCHUNK)
//   [512  .. 1024)  log partials
//   [1024 .. 1536)  cnt partials
//   [2048 .. 2208)  pointvals (Bn*10)
#define WS_SIG 0
#define WS_LOG 512
#define WS_CNT 1024
#define WS_PV  2048

__device__ __forceinline__ float softplusf(float x) {   // stable log(1+exp(x))
    return fmaxf(x, 0.0f) + log1pf(expf(-fabsf(x)));
}
__device__ __forceinline__ float sigmoidf(float x) {
    return 1.0f / (1.0f + expf(-x));
}
__device__ __forceinline__ float wave_sum(float v) {
    for (int off = 32; off > 0; off >>= 1) v += __shfl_down(v, off);
    return __shfl(v, 0);
}

// ---------------- kernel A: point work (16 blocks) + plane chunks (512) -----
__global__ __launch_bounds__(256) void partial_kernel(const float* __restrict__ out,
                                                      const float* __restrict__ tgt,
                                                      float* __restrict__ ws) {
    const int tid = threadIdx.x;

    if (blockIdx.x < Bn) {
        // ======== point work: one wave per sample, dispatched FIRST ========
        if (tid >= 64) return;
        const int b    = blockIdx.x;
        const int lane = tid;

        const float* t = tgt + (size_t)b * Nn * 7;
        const bool active = lane < Nn;
        float tx = 0.0f, ty = 0.0f, t2 = 0.0f, t3 = 1.0f, t4 = 1.0f, t5 = 1.0f, ang = 0.0f;
        int key = -1;
        if (active) {
            tx = t[lane * 7 + 0] * 2.0f;
            ty = t[lane * 7 + 1] * 2.0f;
            t2 = t[lane * 7 + 2];
            t3 = t[lane * 7 + 3];
            t4 = t[lane * 7 + 4];
            t5 = t[lane * 7 + 5];
            ang = t[lane * 7 + 6];
            int dx = (int)floorf(tx);
            int dy = (int)floorf(ty);
            key = dx * Wn + dy;
        }

        // first-occurrence dedupe via shuffles (mask semantics: unique cells)
        bool isfirst = active;
        #pragma unroll 1
        for (int m = 0; m < Nn; ++m) {
            int km = __shfl(key, m);
            if (active && m < lane && km == key) isfirst = false;
        }

        // gather the 10 channels at the point
        const float* base = out + (size_t)b * Cn * PLANE;
        float g[10];
        #pragma unroll
        for (int c = 0; c < 10; ++c) g[c] = active ? base[(size_t)c * PLANE + key] : 0.0f;

        // corrections for masked (unique) points
        float c_sig = 0.0f, c_log = 0.0f, c_cnt = 0.0f, c_n = 0.0f;
        if (isfirst) {
            float p = sigmoidf(g[0]);
            c_sig = p;
            c_n = 1.0f;
            if (p > BKG_THRESH) {
                c_cnt = 1.0f;
                c_log = fmaxf(-softplusf(g[0]), LOG_CLAMP);
            }
        }

        // per-point losses (ALL 50 points, duplicates included)
        float v_obj = 0.0f, v_xyz = 0.0f, v_hwl = 0.0f, v_acl = 0.0f, v_asin = 0.0f;
        if (active) {
            v_obj = -fmaxf(-softplusf(-g[0]), LOG_CLAMP);

            float fx = tx - floorf(tx);
            float fy = ty - floorf(ty);
            float tz = t2 * 0.25f;                 // / ZSIZE (=4.0)
            float e0 = sigmoidf(g[1]) - fx;
            float e1 = sigmoidf(g[2]) - fy;
            float e2 = sigmoidf(g[3]) - tz;
            v_xyz = e0 * e0 + e1 * e1 + e2 * e2;

            float h0 = g[4] - logf(t3 / 1.52f);
            float h1 = g[5] - logf(t4 / 1.63f);
            float h2 = g[6] - logf(t5 / 3.88f);
            v_hwl = h0 * h0 + h1 * h1 + h2 * h2;

            float m = fmaxf(g[7], g[8]);
            float lse = m + logf(expf(g[7] - m) + expf(g[8] - m));
            float gsel = (ang >= 0.0f) ? g[8] : g[7];
            v_acl = lse - gsel;

            float d = sinf(g[9]) - sinf(sinf(ang));
            float ad = fabsf(d);
            v_asin = (ad < 1.0f) ? 0.5f * d * d : ad - 0.5f;
        }
        v_obj  = wave_sum(v_obj);
        v_xyz  = wave_sum(v_xyz);
        v_hwl  = wave_sum(v_hwl);
        v_acl  = wave_sum(v_acl);
        v_asin = wave_sum(v_asin);
        c_sig  = wave_sum(c_sig);
        c_log  = wave_sum(c_log);
        c_cnt  = wave_sum(c_cnt);
        c_n    = wave_sum(c_n);

        if (lane == 0) {
            float* pv = ws + WS_PV + (size_t)b * 10;
            pv[0] = v_obj;  pv[1] = v_xyz; pv[2] = v_hwl; pv[3] = v_acl; pv[4] = v_asin;
            pv[5] = c_sig;  pv[6] = c_log; pv[7] = c_cnt; pv[8] = c_n;
        }
        return;
    }

    // ======== plane chunk reduce over channel-0 plane ========
    const int idx = blockIdx.x - Bn;
    const int b  = idx >> 5;
    const int ch = idx & 31;
    const float4* plane = (const float4*)(out + (size_t)b * Cn * PLANE);
    const int i0 = ch * VPER + tid;

    float4 v0 = plane[i0];
    float4 v1 = plane[i0 + 256];
    float4 v2 = plane[i0 + 512];
    float4 v3 = plane[i0 + 768];

    float s_sig = 0.0f, s_log = 0.0f, s_cnt = 0.0f;
    float xs[16];
    xs[0]=v0.x; xs[1]=v0.y; xs[2]=v0.z; xs[3]=v0.w;
    xs[4]=v1.x; xs[5]=v1.y; xs[6]=v1.z; xs[7]=v1.w;
    xs[8]=v2.x; xs[9]=v2.y; xs[10]=v2.z; xs[11]=v2.w;
    xs[12]=v3.x; xs[13]=v3.y; xs[14]=v3.z; xs[15]=v3.w;
    #pragma unroll
    for (int k = 0; k < 16; ++k) {
        float x = xs[k];
        // shared transcendental: e = exp(-|x|); sigmoid & softplus from it
        float e   = expf(-fabsf(x));
        float inv = 1.0f / (1.0f + e);
        float p   = (x >= 0.0f) ? inv : e * inv;
        float sp  = fmaxf(x, 0.0f) + log1pf(e);   // softplus(x)
        s_sig += p;
        bool sel = p > BKG_THRESH;
        s_cnt += sel ? 1.0f : 0.0f;
        s_log += sel ? fmaxf(-sp, LOG_CLAMP) : 0.0f;
    }
    if (tid < VPER - 1024) {   // 76 tail threads
        float4 v4 = plane[i0 + 1024];
        float ys[4] = {v4.x, v4.y, v4.z, v4.w};
        #pragma unroll
        for (int k = 0; k < 4; ++k) {
            float x = ys[k];
            float e   = expf(-fabsf(x));
            float inv = 1.0f / (1.0f + e);
            float p   = (x >= 0.0f) ? inv : e * inv;
            float sp  = fmaxf(x, 0.0f) + log1pf(e);
            s_sig += p;
            bool sel = p > BKG_THRESH;
            s_cnt += sel ? 1.0f : 0.0f;
            s_log += sel ? fmaxf(-sp, LOG_CLAMP) : 0.0f;
        }
    }

    s_sig = wave_sum(s_sig);
    s_log = wave_sum(s_log);
    s_cnt = wave_sum(s_cnt);

    __shared__ float sh[4][3];
    const int wv = tid >> 6, lane6 = tid & 63;
    if (lane6 == 0) { sh[wv][0] = s_sig; sh[wv][1] = s_log; sh[wv][2] = s_cnt; }
    __syncthreads();
    if (tid == 0) {
        const int slot = b * NCHUNK + ch;
        ws[WS_SIG + slot] = sh[0][0] + sh[1][0] + sh[2][0] + sh[3][0];
        ws[WS_LOG + slot] = sh[0][1] + sh[1][1] + sh[2][1] + sh[3][1];
        ws[WS_CNT + slot] = sh[0][2] + sh[1][2] + sh[2][2] + sh[3][2];
    }
}

// ---------------- kernel B: combine + finalize (1 block, 16 waves) ----------
__global__ __launch_bounds__(1024) void finalize_kernel(const float* __restrict__ ws,
                                                        float* __restrict__ out7) {
    const int b    = threadIdx.x >> 6;   // wave = sample
    const int lane = threadIdx.x & 63;

    // coalesced SoA reads: 32 consecutive floats per array per wave
    float s_sig = 0.0f, s_log = 0.0f, s_cnt = 0.0f;
    if (lane < NCHUNK) {
        const int slot = b * NCHUNK + lane;
        s_sig = ws[WS_SIG + slot];
        s_log = ws[WS_LOG + slot];
        s_cnt = ws[WS_CNT + slot];
    }
    s_sig = wave_sum(s_sig);
    s_log = wave_sum(s_log);
    s_cnt = wave_sum(s_cnt);

    __shared__ float sh_terms[Bn][6];
    if (lane == 0) {
        const float* pv = ws + WS_PV + (size_t)b * 10;
        float v_obj = pv[0], v_xyz = pv[1], v_hwl = pv[2], v_acl = pv[3], v_asin = pv[4];
        float c_sig = pv[5], c_log = pv[6], c_cnt = pv[7], c_n = pv[8];

        float nbkg    = (float)PLANE - c_n;
        float sig_bkg = s_sig - c_sig;
        float clsscale = expf(-3.0f * sig_bkg / nbkg) * 2.5f;

        float cnt  = s_cnt - c_cnt;
        float slog = s_log - c_log;
        float bkg_l = (cnt > 0.0f) ? (-slog / fmaxf(cnt, 1.0f)) : 0.0f;

        const float invN  = 1.0f / (float)Nn;
        const float invN3 = 1.0f / (float)(Nn * 3);

        sh_terms[b][0] = bkg_l;
        sh_terms[b][1] = v_obj * invN * clsscale;
        sh_terms[b][2] = v_xyz * invN3;
        sh_terms[b][3] = v_hwl * invN3 * 0.5f;
        sh_terms[b][4] = v_acl * invN * 0.5f;
        sh_terms[b][5] = v_asin * invN * 0.5f;
    }
    __syncthreads();

    if (threadIdx.x == 0) {
        float s[6] = {0, 0, 0, 0, 0, 0};
        for (int bb = 0; bb < Bn; ++bb)
            for (int j = 0; j < 6; ++j)
                s[j] += sh_terms[bb][j];
        float tot = 0.0f;
        for (int j = 0; j < 6; ++j) tot += s[j];
        out7[0] = tot;
        for (int j = 0; j < 6; ++j) out7[1 + j] = s[j];
    }
}

extern "C" void kernel_launch(void* const* d_in, const int* in_sizes, int n_in,
                              void* d_out, int out_size, void* d_ws, size_t ws_size,
                              hipStream_t stream) {
    const float* out = (const float*)d_in[0];   // (B, C, H, W) f32
    const float* tgt = (const float*)d_in[1];   // (B, N, 7)   f32
    float* o  = (float*)d_out;                  // 7 floats
    float* ws = (float*)d_ws;

    partial_kernel<<<Bn * NCHUNK + Bn, 256, 0, stream>>>(out, tgt, ws);
    finalize_kernel<<<1, 1024, 0, stream>>>(ws, o);
}